// Round 4
// baseline (750.399 us; speedup 1.0000x reference)
//
#include <hip/hip_runtime.h>
#include <math.h>

#define B_    2048
#define S_    134
#define E_    256
#define H_    1024
#define T_    5
#define KK_   6
#define NROWS (B_*T_)          // 10240
#define R_    16               // rows per block
#define NBLK  (NROWS/R_)       // 640

// output layout (flat concat in return order)
#define OFF_LOGITS 1
#define OFF_SCORES (OFF_LOGITS + NROWS*12)   // 122881
#define OFF_SEL    (OFF_SCORES + NROWS*6)    // 184321
#define OFF_LPK    (OFF_SEL + NROWS*2)       // 204801

// GEMM2 over an 8-row half staged in hs[8][H_]; x from resident xs LDS.
// rowbase = 0 or 8.
template<int NOUT>
__device__ __forceinline__ void gemm2_half(
    const float (*xs)[E_], int g0, int rowbase,
    const float (*hs)[H_],
    const float* __restrict__ w2, const float* __restrict__ b2,
    float* osh, float* __restrict__ gout, int tid)
{
    const int wave = tid >> 6;
    const int lane = tid & 63;

    float p[2][NOUT];
#pragma unroll
    for (int rr = 0; rr < 2; ++rr)
#pragma unroll
        for (int n = 0; n < NOUT; ++n) p[rr][n] = 0.f;

    const int jbase = lane * 20;
#pragma unroll
    for (int jj = 0; jj < 20; ++jj) {
        const int j = jbase + jj;
        float w2r[NOUT];
#pragma unroll
        for (int n = 0; n < NOUT; ++n) w2r[n] = w2[(size_t)j*NOUT + n];
#pragma unroll
        for (int rr = 0; rr < 2; ++rr) {
            const int lr = wave*2 + rr;               // 0..7 in this half
            float v = (j < E_) ? xs[rowbase + lr][j] : hs[lr][j - E_];
#pragma unroll
            for (int n = 0; n < NOUT; ++n) p[rr][n] += v * w2r[n];
        }
    }
    // butterfly reduce across the wave
#pragma unroll
    for (int rr = 0; rr < 2; ++rr)
#pragma unroll
        for (int n = 0; n < NOUT; ++n)
#pragma unroll
            for (int off = 32; off > 0; off >>= 1)
                p[rr][n] += __shfl_xor(p[rr][n], off, 64);

    if (lane == 0) {
#pragma unroll
        for (int rr = 0; rr < 2; ++rr) {
            const int lr = wave*2 + rr;
            const int g  = g0 + rowbase + lr;
#pragma unroll
            for (int n = 0; n < NOUT; ++n) {
                float v = p[rr][n] + b2[n];
                osh[(rowbase + lr)*NOUT + n] = v;
                gout[(size_t)g*NOUT + n] = v;
            }
        }
    }
}

// One decoder phase: GEMM1 (x@w1+b1) -> LayerNorm -> ReLU -> GEMM2 ([x,h]@w2+b2)
template<int NOUT>
__device__ __forceinline__ void decoder_phase(
    const float (*xs)[E_],
    const float* __restrict__ w1, const float* __restrict__ b1,
    const float* __restrict__ ga, const float* __restrict__ be,
    const float* __restrict__ w2, const float* __restrict__ b2,
    float (*hs)[H_], float (*red)[4][2], float* mu_s, float* rs_s,
    float* osh, float* __restrict__ gout, int g0, int tid)
{
    const int wave = tid >> 6;
    const int lane = tid & 63;
    const int j0   = tid * 4;

    // ---- GEMM1: acc[r][c] = xs[r][:] . w1[:, j0+c] ----
    float acc[R_][4];
#pragma unroll
    for (int r = 0; r < R_; ++r) {
        acc[r][0] = 0.f; acc[r][1] = 0.f; acc[r][2] = 0.f; acc[r][3] = 0.f;
    }

    for (int k0 = 0; k0 < E_; k0 += 8) {
        // batch 8 coalesced float4 loads of w1 (8 VMEM in flight)
        float4 w[8];
#pragma unroll
        for (int kk = 0; kk < 8; ++kk)
            w[kk] = *(const float4*)(w1 + (size_t)(k0 + kk)*H_ + j0);
#pragma unroll
        for (int r = 0; r < R_; ++r) {
            float4 xa = *(const float4*)&xs[r][k0];     // wave-uniform -> LDS broadcast
            float4 xb = *(const float4*)&xs[r][k0+4];
            acc[r][0] += xa.x*w[0].x; acc[r][1] += xa.x*w[0].y; acc[r][2] += xa.x*w[0].z; acc[r][3] += xa.x*w[0].w;
            acc[r][0] += xa.y*w[1].x; acc[r][1] += xa.y*w[1].y; acc[r][2] += xa.y*w[1].z; acc[r][3] += xa.y*w[1].w;
            acc[r][0] += xa.z*w[2].x; acc[r][1] += xa.z*w[2].y; acc[r][2] += xa.z*w[2].z; acc[r][3] += xa.z*w[2].w;
            acc[r][0] += xa.w*w[3].x; acc[r][1] += xa.w*w[3].y; acc[r][2] += xa.w*w[3].z; acc[r][3] += xa.w*w[3].w;
            acc[r][0] += xb.x*w[4].x; acc[r][1] += xb.x*w[4].y; acc[r][2] += xb.x*w[4].z; acc[r][3] += xb.x*w[4].w;
            acc[r][0] += xb.y*w[5].x; acc[r][1] += xb.y*w[5].y; acc[r][2] += xb.y*w[5].z; acc[r][3] += xb.y*w[5].w;
            acc[r][0] += xb.z*w[6].x; acc[r][1] += xb.z*w[6].y; acc[r][2] += xb.z*w[6].z; acc[r][3] += xb.z*w[6].w;
            acc[r][0] += xb.w*w[7].x; acc[r][1] += xb.w*w[7].y; acc[r][2] += xb.w*w[7].z; acc[r][3] += xb.w*w[7].w;
        }
    }

    // bias
    {
        float4 bv = *(const float4*)(b1 + j0);
#pragma unroll
        for (int r = 0; r < R_; ++r) {
            acc[r][0] += bv.x; acc[r][1] += bv.y; acc[r][2] += bv.z; acc[r][3] += bv.w;
        }
    }

    // ---- LayerNorm stats: per-row sum / sumsq across 1024 cols ----
#pragma unroll
    for (int r = 0; r < R_; ++r) {
        float s  = acc[r][0] + acc[r][1] + acc[r][2] + acc[r][3];
        float ss = acc[r][0]*acc[r][0] + acc[r][1]*acc[r][1]
                 + acc[r][2]*acc[r][2] + acc[r][3]*acc[r][3];
#pragma unroll
        for (int off = 32; off > 0; off >>= 1) {
            s  += __shfl_xor(s,  off, 64);
            ss += __shfl_xor(ss, off, 64);
        }
        if (lane == 0) { red[r][wave][0] = s; red[r][wave][1] = ss; }
    }
    __syncthreads();
    if (tid < R_) {
        float s  = red[tid][0][0] + red[tid][1][0] + red[tid][2][0] + red[tid][3][0];
        float ss = red[tid][0][1] + red[tid][1][1] + red[tid][2][1] + red[tid][3][1];
        float mu  = s * (1.0f / H_);
        float var = ss * (1.0f / H_) - mu * mu;
        mu_s[tid] = mu;
        rs_s[tid] = rsqrtf(var + 1e-5f);
    }
    __syncthreads();

    // ---- LN apply + ReLU in registers (h replaces acc) ----
    {
        float4 gv = *(const float4*)(ga + j0);
        float4 bv = *(const float4*)(be + j0);
#pragma unroll
        for (int r = 0; r < R_; ++r) {
            float mu = mu_s[r], rs = rs_s[r];
            float h0 = gv.x * ((acc[r][0] - mu) * rs) + bv.x;
            float h1 = gv.y * ((acc[r][1] - mu) * rs) + bv.y;
            float h2 = gv.z * ((acc[r][2] - mu) * rs) + bv.z;
            float h3 = gv.w * ((acc[r][3] - mu) * rs) + bv.w;
            acc[r][0] = h0 > 0.f ? h0 : 0.f;
            acc[r][1] = h1 > 0.f ? h1 : 0.f;
            acc[r][2] = h2 > 0.f ? h2 : 0.f;
            acc[r][3] = h3 > 0.f ? h3 : 0.f;
        }
    }

    // ---- GEMM2 in two 8-row halves through hs (rows 8..15 stay in regs) ----
#pragma unroll
    for (int r = 0; r < 8; ++r)
        *(float4*)&hs[r][j0] = *(float4*)&acc[r][0];
    __syncthreads();
    gemm2_half<NOUT>(xs, g0, 0, hs, w2, b2, osh, gout, tid);
    __syncthreads();
#pragma unroll
    for (int r = 0; r < 8; ++r)
        *(float4*)&hs[r][j0] = *(float4*)&acc[8 + r][0];
    __syncthreads();
    gemm2_half<NOUT>(xs, g0, 8, hs, w2, b2, osh, gout, tid);
    __syncthreads();
}

__global__ __launch_bounds__(256, 2)
void kp_fused(const float* __restrict__ hid,  const float* __restrict__ fkp,
              const float* __restrict__ w1ld, const float* __restrict__ b1ld,
              const float* __restrict__ gld,  const float* __restrict__ btld,
              const float* __restrict__ w2ld, const float* __restrict__ b2ld,
              const float* __restrict__ w1sd, const float* __restrict__ b1sd,
              const float* __restrict__ gsd,  const float* __restrict__ btsd,
              const float* __restrict__ w2sd, const float* __restrict__ b2sd,
              const int* __restrict__ ctx,
              float* __restrict__ out, float* __restrict__ ws)
{
    __shared__ float hs[8][H_];         // 32 KB: half of post-LN hidden
    __shared__ float xs[R_][E_];        // 16 KB: staged input rows (resident)
    __shared__ float red[R_][4][2];     // cross-wave LN partials
    __shared__ float mu_s[R_], rs_s[R_];
    __shared__ float lo_s[R_*12];       // logits stash for epilogue
    __shared__ float sc_s[R_*6];        // scores stash for epilogue

    const int tid = threadIdx.x;
    const int g0  = blockIdx.x * R_;
    const int kp0 = ctx[0] - 1;

    // ---- stage x rows into LDS: thread t -> row t>>4, floats (t&15)*16 .. +15
    {
        const int r   = tid >> 4;
        const int off = (tid & 15) * 16;
        const int g = g0 + r;
        const int b = g / T_;
        const int t = g - b * T_;
        const float* src = hid + (size_t)(b * S_ + kp0 + t) * E_ + off;
#pragma unroll
        for (int q = 0; q < 4; ++q)
            *(float4*)&xs[r][off + 4*q] = *(const float4*)(src + 4*q);
    }
    __syncthreads();

    decoder_phase<12>(xs, w1ld, b1ld, gld, btld, w2ld, b2ld,
                      hs, red, mu_s, rs_s, lo_s, out + OFF_LOGITS, g0, tid);
    decoder_phase<6>(xs, w1sd, b1sd, gsd, btsd, w2sd, b2sd,
                     hs, red, mu_s, rs_s, sc_s, out + OFF_SCORES, g0, tid);

    // ---- per-row loss epilogue ----
    if (tid < R_) {
        const int g = g0 + tid;
        const int b = g / T_;
        const int t = g - b * T_;
        const float y0 = fkp[b*(T_*2) + t*2 + 0];
        const float y1 = fkp[b*(T_*2) + t*2 + 1];

        float best = 1e30f; int am = 0;
#pragma unroll
        for (int k = 0; k < KK_; ++k) {
            float dx = lo_s[tid*12 + 2*k + 0] - y0;
            float dy = lo_s[tid*12 + 2*k + 1] - y1;
            float L = dx*dx + dy*dy;
            if (L < best) { best = L; am = k; }  // strict <: first-min like jnp.argmin
        }

        // softmax(scores) then log_softmax(softmax) (faithful double softmax)
        float m = -1e30f;
#pragma unroll
        for (int k = 0; k < KK_; ++k) m = fmaxf(m, sc_s[tid*6 + k]);
        float e[KK_]; float ssum = 0.f;
#pragma unroll
        for (int k = 0; k < KK_; ++k) { e[k] = expf(sc_s[tid*6 + k] - m); ssum += e[k]; }
        const float inv = 1.0f / ssum;
        float lse = 0.f, sm_am = 0.f;
#pragma unroll
        for (int k = 0; k < KK_; ++k) {
            float smk = e[k] * inv;
            lse += expf(smk);
            if (k == am) sm_am = smk;
        }
        const float ce = logf(lse) - sm_am;   // -(sm[am] - logsumexp(sm))

        out[OFF_SEL + g*2 + 0] = lo_s[tid*12 + 2*am + 0];
        out[OFF_SEL + g*2 + 1] = lo_s[tid*12 + 2*am + 1];

        atomicAdd(&ws[t],       best);  // sum over B of min_loss, per t
        atomicAdd(&ws[T_ + t],  ce);    // sum over B of ce, per t
    }
}

__global__ void kp_finalize(const float* __restrict__ ws, float* __restrict__ out)
{
    if (threadIdx.x == 0 && blockIdx.x == 0) {
        const float wts[T_] = {1e-4f, 1e-3f, 1e-2f, 1e-1f, 1.0f}; // 0.1^(4-t)
        float s = 0.f;
#pragma unroll
        for (int t = 0; t < T_; ++t) {
            float ml = ws[t]      * (1.0f / B_);
            float ce = ws[T_ + t] * (1.0f / B_);
            float l  = ml * wts[t] + ce;
            out[OFF_LPK + t] = l;
            s += l;
        }
        out[0] = s * (1.0f / T_);   // kp_loss (rescale = 1.0)
    }
}

extern "C" void kernel_launch(void* const* d_in, const int* in_sizes, int n_in,
                              void* d_out, int out_size, void* d_ws, size_t ws_size,
                              hipStream_t stream)
{
    const float* hid  = (const float*)d_in[0];
    const float* fkp  = (const float*)d_in[1];
    const float* w1ld = (const float*)d_in[2];
    const float* b1ld = (const float*)d_in[3];
    const float* gld  = (const float*)d_in[4];
    const float* btld = (const float*)d_in[5];
    const float* w2ld = (const float*)d_in[6];
    const float* b2ld = (const float*)d_in[7];
    const float* w1sd = (const float*)d_in[8];
    const float* b1sd = (const float*)d_in[9];
    const float* gsd  = (const float*)d_in[10];
    const float* btsd = (const float*)d_in[11];
    const float* w2sd = (const float*)d_in[12];
    const float* b2sd = (const float*)d_in[13];
    const int*   ctx  = (const int*)d_in[14];
    float* out = (float*)d_out;
    float* ws  = (float*)d_ws;

    // zero the 10 loss accumulators (ws is poisoned 0xAA before every launch)
    hipMemsetAsync(ws, 0, 2 * T_ * sizeof(float), stream);

    kp_fused<<<NBLK, 256, 0, stream>>>(hid, fkp,
                                       w1ld, b1ld, gld, btld, w2ld, b2ld,
                                       w1sd, b1sd, gsd, btsd, w2sd, b2sd,
                                       ctx, out, ws);
    kp_finalize<<<1, 64, 0, stream>>>(ws, out);
}

// Round 5
// 586.567 us; speedup vs baseline: 1.2793x; 1.2793x over previous
//
#include <hip/hip_runtime.h>
#include <math.h>

#define B_    2048
#define S_    134
#define E_    256
#define H_    1024
#define T_    5
#define KK_   6
#define NROWS (B_*T_)          // 10240
#define R_    8                // rows per block (16 spills — measured r3/r4)
#define NBLK  (NROWS/R_)       // 1280

// output layout (flat concat in return order)
#define OFF_LOGITS 1
#define OFF_SCORES (OFF_LOGITS + NROWS*12)   // 122881
#define OFF_SEL    (OFF_SCORES + NROWS*6)    // 184321
#define OFF_LPK    (OFF_SEL + NROWS*2)       // 204801

// GEMM2 over a 4-row half staged in hs[4][H_]; x from resident xs LDS.
// Each wave handles one row: row = rowbase + wave. Lane owns j in [20*lane, 20*lane+20).
template<int NOUT>
__device__ __forceinline__ void gemm2_half(
    const float (*xs)[E_], int g0, int rowbase,
    const float (*hs)[H_],
    const float* __restrict__ w2, const float* __restrict__ b2,
    float* osh, float* __restrict__ gout, int tid)
{
    const int wave = tid >> 6;
    const int lane = tid & 63;
    const int lr   = wave;                    // 0..3 within this half

    float p[NOUT];
#pragma unroll
    for (int n = 0; n < NOUT; ++n) p[n] = 0.f;

    const int jbase = lane * 20;
#pragma unroll
    for (int jj = 0; jj < 20; ++jj) {
        const int j = jbase + jj;
        // w2 row is contiguous (NOUT floats) -> vector loads
        float w2r[NOUT];
        if (NOUT == 12) {
            float4 a = *(const float4*)(w2 + (size_t)j*NOUT);
            float4 b = *(const float4*)(w2 + (size_t)j*NOUT + 4);
            float4 c = *(const float4*)(w2 + (size_t)j*NOUT + 8);
            w2r[0]=a.x; w2r[1]=a.y; w2r[2]=a.z; w2r[3]=a.w;
            w2r[4]=b.x; w2r[5]=b.y; w2r[6]=b.z; w2r[7]=b.w;
            w2r[8]=c.x; w2r[9]=c.y; w2r[10]=c.z; w2r[11]=c.w;
        } else {
            float4 a = *(const float4*)(w2 + (size_t)j*NOUT);
            float2 b = *(const float2*)(w2 + (size_t)j*NOUT + 4);
            w2r[0]=a.x; w2r[1]=a.y; w2r[2]=a.z; w2r[3]=a.w;
            w2r[4]=b.x; w2r[5]=b.y;
        }
        float v = (j < E_) ? xs[rowbase + lr][j] : hs[lr][j - E_];
#pragma unroll
        for (int n = 0; n < NOUT; ++n) p[n] += v * w2r[n];
    }
    // butterfly reduce across the wave
#pragma unroll
    for (int n = 0; n < NOUT; ++n)
#pragma unroll
        for (int off = 32; off > 0; off >>= 1)
            p[n] += __shfl_xor(p[n], off, 64);

    if (lane == 0) {
        const int g = g0 + rowbase + lr;
#pragma unroll
        for (int n = 0; n < NOUT; ++n) {
            float v = p[n] + b2[n];
            osh[(rowbase + lr)*NOUT + n] = v;
            gout[(size_t)g*NOUT + n] = v;
        }
    }
}

// One decoder phase: GEMM1 (x@w1+b1) -> LayerNorm -> ReLU -> GEMM2 ([x,h]@w2+b2)
template<int NOUT>
__device__ __forceinline__ void decoder_phase(
    const float (*xs)[E_],
    const float* __restrict__ w1, const float* __restrict__ b1,
    const float* __restrict__ ga, const float* __restrict__ be,
    const float* __restrict__ w2, const float* __restrict__ b2,
    float (*hs)[H_], float (*red)[4][2], float* mu_s, float* rs_s,
    float* osh, float* __restrict__ gout, int g0, int tid)
{
    const int wave = tid >> 6;
    const int lane = tid & 63;
    const int j0   = tid * 4;

    // ---- GEMM1: acc[r][c] = xs[r][:] . w1[:, j0+c], register double-buffered ----
    float acc[R_][4];
#pragma unroll
    for (int r = 0; r < R_; ++r) {
        acc[r][0] = 0.f; acc[r][1] = 0.f; acc[r][2] = 0.f; acc[r][3] = 0.f;
    }

    const float* wcol = w1 + j0;
    float4 wa[4], wb[4];
#pragma unroll
    for (int kk = 0; kk < 4; ++kk)
        wa[kk] = *(const float4*)(wcol + (size_t)kk*H_);

    for (int k0 = 0; k0 < E_; k0 += 8) {
        // prefetch second half of this step (k0+4..k0+7)
#pragma unroll
        for (int kk = 0; kk < 4; ++kk)
            wb[kk] = *(const float4*)(wcol + (size_t)(k0+4+kk)*H_);
        // compute with wa (k0..k0+3)
#pragma unroll
        for (int r = 0; r < R_; ++r) {
            float4 xv = *(const float4*)&xs[r][k0];      // LDS broadcast
            acc[r][0] += xv.x*wa[0].x; acc[r][1] += xv.x*wa[0].y; acc[r][2] += xv.x*wa[0].z; acc[r][3] += xv.x*wa[0].w;
            acc[r][0] += xv.y*wa[1].x; acc[r][1] += xv.y*wa[1].y; acc[r][2] += xv.y*wa[1].z; acc[r][3] += xv.y*wa[1].w;
            acc[r][0] += xv.z*wa[2].x; acc[r][1] += xv.z*wa[2].y; acc[r][2] += xv.z*wa[2].z; acc[r][3] += xv.z*wa[2].w;
            acc[r][0] += xv.w*wa[3].x; acc[r][1] += xv.w*wa[3].y; acc[r][2] += xv.w*wa[3].z; acc[r][3] += xv.w*wa[3].w;
        }
        // prefetch first half of next step (k0+8..k0+11)
        if (k0 + 8 < E_) {
#pragma unroll
            for (int kk = 0; kk < 4; ++kk)
                wa[kk] = *(const float4*)(wcol + (size_t)(k0+8+kk)*H_);
        }
        // compute with wb (k0+4..k0+7)
#pragma unroll
        for (int r = 0; r < R_; ++r) {
            float4 xv = *(const float4*)&xs[r][k0+4];    // LDS broadcast
            acc[r][0] += xv.x*wb[0].x; acc[r][1] += xv.x*wb[0].y; acc[r][2] += xv.x*wb[0].z; acc[r][3] += xv.x*wb[0].w;
            acc[r][0] += xv.y*wb[1].x; acc[r][1] += xv.y*wb[1].y; acc[r][2] += xv.y*wb[1].z; acc[r][3] += xv.y*wb[1].w;
            acc[r][0] += xv.z*wb[2].x; acc[r][1] += xv.z*wb[2].y; acc[r][2] += xv.z*wb[2].z; acc[r][3] += xv.z*wb[2].w;
            acc[r][0] += xv.w*wb[3].x; acc[r][1] += xv.w*wb[3].y; acc[r][2] += xv.w*wb[3].z; acc[r][3] += xv.w*wb[3].w;
        }
    }

    // bias
    {
        float4 bv = *(const float4*)(b1 + j0);
#pragma unroll
        for (int r = 0; r < R_; ++r) {
            acc[r][0] += bv.x; acc[r][1] += bv.y; acc[r][2] += bv.z; acc[r][3] += bv.w;
        }
    }

    // ---- LayerNorm stats: per-row sum / sumsq across 1024 cols ----
#pragma unroll
    for (int r = 0; r < R_; ++r) {
        float s  = acc[r][0] + acc[r][1] + acc[r][2] + acc[r][3];
        float ss = acc[r][0]*acc[r][0] + acc[r][1]*acc[r][1]
                 + acc[r][2]*acc[r][2] + acc[r][3]*acc[r][3];
#pragma unroll
        for (int off = 32; off > 0; off >>= 1) {
            s  += __shfl_xor(s,  off, 64);
            ss += __shfl_xor(ss, off, 64);
        }
        if (lane == 0) { red[r][wave][0] = s; red[r][wave][1] = ss; }
    }
    __syncthreads();
    if (tid < R_) {
        float s  = red[tid][0][0] + red[tid][1][0] + red[tid][2][0] + red[tid][3][0];
        float ss = red[tid][0][1] + red[tid][1][1] + red[tid][2][1] + red[tid][3][1];
        float mu  = s * (1.0f / H_);
        float var = ss * (1.0f / H_) - mu * mu;
        mu_s[tid] = mu;
        rs_s[tid] = rsqrtf(var + 1e-5f);
    }
    __syncthreads();

    // ---- LN apply + ReLU in registers (h replaces acc) ----
    {
        float4 gv = *(const float4*)(ga + j0);
        float4 bv = *(const float4*)(be + j0);
#pragma unroll
        for (int r = 0; r < R_; ++r) {
            float mu = mu_s[r], rs = rs_s[r];
            float h0 = gv.x * ((acc[r][0] - mu) * rs) + bv.x;
            float h1 = gv.y * ((acc[r][1] - mu) * rs) + bv.y;
            float h2 = gv.z * ((acc[r][2] - mu) * rs) + bv.z;
            float h3 = gv.w * ((acc[r][3] - mu) * rs) + bv.w;
            acc[r][0] = h0 > 0.f ? h0 : 0.f;
            acc[r][1] = h1 > 0.f ? h1 : 0.f;
            acc[r][2] = h2 > 0.f ? h2 : 0.f;
            acc[r][3] = h3 > 0.f ? h3 : 0.f;
        }
    }

    // ---- GEMM2 in two 4-row halves through hs (rows 4..7 stay in regs) ----
#pragma unroll
    for (int r = 0; r < 4; ++r)
        *(float4*)&hs[r][j0] = *(float4*)&acc[r][0];
    __syncthreads();
    gemm2_half<NOUT>(xs, g0, 0, hs, w2, b2, osh, gout, tid);
    __syncthreads();
#pragma unroll
    for (int r = 0; r < 4; ++r)
        *(float4*)&hs[r][j0] = *(float4*)&acc[4 + r][0];
    __syncthreads();
    gemm2_half<NOUT>(xs, g0, 4, hs, w2, b2, osh, gout, tid);
    __syncthreads();
}

__global__ __launch_bounds__(256, 3)
void kp_fused(const float* __restrict__ hid,  const float* __restrict__ fkp,
              const float* __restrict__ w1ld, const float* __restrict__ b1ld,
              const float* __restrict__ gld,  const float* __restrict__ btld,
              const float* __restrict__ w2ld, const float* __restrict__ b2ld,
              const float* __restrict__ w1sd, const float* __restrict__ b1sd,
              const float* __restrict__ gsd,  const float* __restrict__ btsd,
              const float* __restrict__ w2sd, const float* __restrict__ b2sd,
              const int* __restrict__ ctx,
              float* __restrict__ out, float* __restrict__ ws)
{
    __shared__ float hs[4][H_];         // 16 KB: quarter of post-LN hidden
    __shared__ float xs[R_][E_];        // 8 KB: staged input rows (resident)
    __shared__ float red[R_][4][2];     // cross-wave LN partials
    __shared__ float mu_s[R_], rs_s[R_];
    __shared__ float lo_s[R_*12];       // logits stash for epilogue
    __shared__ float sc_s[R_*6];        // scores stash for epilogue

    const int tid = threadIdx.x;
    const int g0  = blockIdx.x * R_;
    const int kp0 = ctx[0] - 1;

    // ---- stage x rows into LDS (coalesced): thread t -> row t>>5, floats (t&31)*8 .. +7
    {
        const int r   = tid >> 5;
        const int off = (tid & 31) * 8;
        const int g = g0 + r;
        const int b = g / T_;
        const int t = g - b * T_;
        const float* src = hid + (size_t)(b * S_ + kp0 + t) * E_ + off;
        float4 v0 = *(const float4*)(src);
        float4 v1 = *(const float4*)(src + 4);
        *(float4*)&xs[r][off]     = v0;
        *(float4*)&xs[r][off + 4] = v1;
    }
    __syncthreads();

    decoder_phase<12>(xs, w1ld, b1ld, gld, btld, w2ld, b2ld,
                      hs, red, mu_s, rs_s, lo_s, out + OFF_LOGITS, g0, tid);
    decoder_phase<6>(xs, w1sd, b1sd, gsd, btsd, w2sd, b2sd,
                     hs, red, mu_s, rs_s, sc_s, out + OFF_SCORES, g0, tid);

    // ---- per-row loss epilogue ----
    if (tid < R_) {
        const int g = g0 + tid;
        const int b = g / T_;
        const int t = g - b * T_;
        const float y0 = fkp[b*(T_*2) + t*2 + 0];
        const float y1 = fkp[b*(T_*2) + t*2 + 1];

        float best = 1e30f; int am = 0;
#pragma unroll
        for (int k = 0; k < KK_; ++k) {
            float dx = lo_s[tid*12 + 2*k + 0] - y0;
            float dy = lo_s[tid*12 + 2*k + 1] - y1;
            float L = dx*dx + dy*dy;
            if (L < best) { best = L; am = k; }  // strict <: first-min like jnp.argmin
        }

        // softmax(scores) then log_softmax(softmax) (faithful double softmax)
        float m = -1e30f;
#pragma unroll
        for (int k = 0; k < KK_; ++k) m = fmaxf(m, sc_s[tid*6 + k]);
        float e[KK_]; float ssum = 0.f;
#pragma unroll
        for (int k = 0; k < KK_; ++k) { e[k] = expf(sc_s[tid*6 + k] - m); ssum += e[k]; }
        const float inv = 1.0f / ssum;
        float lse = 0.f, sm_am = 0.f;
#pragma unroll
        for (int k = 0; k < KK_; ++k) {
            float smk = e[k] * inv;
            lse += expf(smk);
            if (k == am) sm_am = smk;
        }
        const float ce = logf(lse) - sm_am;   // -(sm[am] - logsumexp(sm))

        out[OFF_SEL + g*2 + 0] = lo_s[tid*12 + 2*am + 0];
        out[OFF_SEL + g*2 + 1] = lo_s[tid*12 + 2*am + 1];

        atomicAdd(&ws[t],       best);  // sum over B of min_loss, per t
        atomicAdd(&ws[T_ + t],  ce);    // sum over B of ce, per t
    }
}

__global__ void kp_finalize(const float* __restrict__ ws, float* __restrict__ out)
{
    if (threadIdx.x == 0 && blockIdx.x == 0) {
        const float wts[T_] = {1e-4f, 1e-3f, 1e-2f, 1e-1f, 1.0f}; // 0.1^(4-t)
        float s = 0.f;
#pragma unroll
        for (int t = 0; t < T_; ++t) {
            float ml = ws[t]      * (1.0f / B_);
            float ce = ws[T_ + t] * (1.0f / B_);
            float l  = ml * wts[t] + ce;
            out[OFF_LPK + t] = l;
            s += l;
        }
        out[0] = s * (1.0f / T_);   // kp_loss (rescale = 1.0)
    }
}

extern "C" void kernel_launch(void* const* d_in, const int* in_sizes, int n_in,
                              void* d_out, int out_size, void* d_ws, size_t ws_size,
                              hipStream_t stream)
{
    const float* hid  = (const float*)d_in[0];
    const float* fkp  = (const float*)d_in[1];
    const float* w1ld = (const float*)d_in[2];
    const float* b1ld = (const float*)d_in[3];
    const float* gld  = (const float*)d_in[4];
    const float* btld = (const float*)d_in[5];
    const float* w2ld = (const float*)d_in[6];
    const float* b2ld = (const float*)d_in[7];
    const float* w1sd = (const float*)d_in[8];
    const float* b1sd = (const float*)d_in[9];
    const float* gsd  = (const float*)d_in[10];
    const float* btsd = (const float*)d_in[11];
    const float* w2sd = (const float*)d_in[12];
    const float* b2sd = (const float*)d_in[13];
    const int*   ctx  = (const int*)d_in[14];
    float* out = (float*)d_out;
    float* ws  = (float*)d_ws;

    // zero the 10 loss accumulators (ws is poisoned 0xAA before every launch)
    hipMemsetAsync(ws, 0, 2 * T_ * sizeof(float), stream);

    kp_fused<<<NBLK, 256, 0, stream>>>(hid, fkp,
                                       w1ld, b1ld, gld, btld, w2ld, b2ld,
                                       w1sd, b1sd, gsd, btsd, w2sd, b2sd,
                                       ctx, out, ws);
    kp_finalize<<<1, 64, 0, stream>>>(ws, out);
}